// Round 4
// baseline (329.254 us; speedup 1.0000x reference)
//
#include <hip/hip_runtime.h>
#include <hip/hip_bf16.h>
#include <math.h>

#define DIM 1024
#define HID 2048
#define NE  4
#define NT  4096            // B*T tokens
#define KW  (NE*HID)        // 8192, GEMM2 K / Hw leading dim
#define KSPLIT 4
#define KCH (KW / KSPLIT)   // 2048 per split

typedef __attribute__((ext_vector_type(8))) short short8;
typedef __attribute__((ext_vector_type(4))) short short4v;
typedef __attribute__((ext_vector_type(4))) float floatx4;

// ---- helpers ----------------------------------------------------------------

__device__ __forceinline__ void async_cp16(const void* g, void* l) {
  __builtin_amdgcn_global_load_lds(
      (const __attribute__((address_space(1))) void*)g,
      (__attribute__((address_space(3))) void*)l, 16, 0, 0);
}

__device__ __forceinline__ short f2bf(float f) {
  union { float f; unsigned u; } x; x.f = f;
  unsigned r = x.u + 0x7fffu + ((x.u >> 16) & 1u);   // round-to-nearest-even
  return (short)(r >> 16);
}

// fast GELU (tanh form via sigmoid + v_exp/v_rcp); |err| ~2e-4 vs exact
__device__ __forceinline__ float gelu_fast(float v) {
  float u = 1.595769122f * (v + 0.044715f * v * v * v);
  return v * __builtin_amdgcn_rcpf(1.0f + __expf(-u));
}

// ---- router + x->bf16: weights = softmax(x@Wr+br); xb = bf16(x) -------------
// one wave per token; float4 loads (16B/lane), short4 stores (8B/lane)
__global__ void router_cvt(const float* __restrict__ x, const float* __restrict__ Wr,
                           const float* __restrict__ br, float* __restrict__ wgt,
                           short* __restrict__ xb) {
  const int wv = threadIdx.x >> 6, lane = threadIdx.x & 63;
  const int t = blockIdx.x * 4 + wv;
  const float* xr = x + (size_t)t * DIM;
  short* xo = xb + (size_t)t * DIM;
  float a0 = 0.f, a1 = 0.f, a2 = 0.f, a3 = 0.f;
  #pragma unroll
  for (int p = 0; p < 4; p++) {
    const int d = p * 256 + lane * 4;
    floatx4 v = *(const floatx4*)&xr[d];
    short4v o;
    #pragma unroll
    for (int j = 0; j < 4; j++) {
      o[j] = f2bf(v[j]);
      floatx4 wr = *(const floatx4*)&Wr[(d + j) * 4];
      a0 += v[j] * wr[0]; a1 += v[j] * wr[1];
      a2 += v[j] * wr[2]; a3 += v[j] * wr[3];
    }
    *(short4v*)&xo[d] = o;
  }
  #pragma unroll
  for (int off = 32; off; off >>= 1) {
    a0 += __shfl_down(a0, off);
    a1 += __shfl_down(a1, off);
    a2 += __shfl_down(a2, off);
    a3 += __shfl_down(a3, off);
  }
  a0 = __shfl(a0, 0); a1 = __shfl(a1, 0); a2 = __shfl(a2, 0); a3 = __shfl(a3, 0);
  float s0 = a0 + br[0], s1 = a1 + br[1], s2 = a2 + br[2], s3 = a3 + br[3];
  float m = fmaxf(fmaxf(s0, s1), fmaxf(s2, s3));
  float e0 = __expf(s0 - m), e1 = __expf(s1 - m), e2 = __expf(s2 - m), e3 = __expf(s3 - m);
  float inv = 1.f / (e0 + e1 + e2 + e3);
  float v = (lane == 0) ? e0 : (lane == 1) ? e1 : (lane == 2) ? e2 : e3;
  if (lane < 4) wgt[t * 4 + lane] = v * inv;
}

// ---- fast fp32 [z][R][C] -> bf16 [z][C][R] transpose+convert ----------------
// tile 128 rows x 32 cols; float4 reads (16B/lane), b128 LDS reads + short8
// global writes (16B/lane, 128B contiguous per 8 lanes).
#define TP_PADR 136   // LDS row stride (shorts); 272B, 16B-aligned
__global__ void transpose_cvt_fast(const float* __restrict__ in, short* __restrict__ out,
                                   int R, int C) {
  __shared__ __align__(16) short tile[32 * TP_PADR];
  const size_t zo = (size_t)blockIdx.z * (size_t)R * C;
  const int c0 = blockIdx.x * 32, r0 = blockIdx.y * 128;
  const int t = threadIdx.x;
  const int cin = (t & 7) * 4;
  const int rin = t >> 3;                 // 0..31
  #pragma unroll
  for (int i = 0; i < 4; i++) {
    const int r = rin + i * 32;
    floatx4 v = *(const floatx4*)&in[zo + (size_t)(r0 + r) * C + c0 + cin];
    #pragma unroll
    for (int j = 0; j < 4; j++)
      tile[(cin + j) * TP_PADR + r] = f2bf(v[j]);
  }
  __syncthreads();
  const int ct = t >> 3;                  // 0..31
  #pragma unroll
  for (int i = 0; i < 2; i++) {
    const int rc = (t & 7) + 8 * i;       // 0..15, 8-short chunks
    short8 vv = *(const short8*)&tile[ct * TP_PADR + rc * 8];
    *(short8*)&out[zo + (size_t)(c0 + ct) * R + r0 + rc * 8] = vv;
  }
}

// ---- bias_init: out[t][d] = sum_e wgt[t][e]*b2[e][d] ------------------------
__global__ void bias_init(const float* __restrict__ wgt, const float* __restrict__ b2,
                          float* __restrict__ out) {
  const int i = (blockIdx.x * 256 + threadIdx.x) * 4;
  const int t = i >> 10, d = i & (DIM - 1);
  floatx4 w = *(const floatx4*)&wgt[t * 4];
  floatx4 r = (floatx4)0.f;
  #pragma unroll
  for (int e = 0; e < 4; e++) {
    floatx4 bv = *(const floatx4*)&b2[e * DIM + d];
    r += w[e] * bv;
  }
  *(floatx4*)&out[i] = r;
}

// ============================================================================
// GEMM tiles: 128x128, BK=64 (LDS 2x16KB), bf16 16x16x32 MFMA, 4 waves.
// LDS row stride 64 shorts (128B = all 32 banks); the 8x16B k-slots of row r
// hold k-block (pos ^ (r&7)) -> conflict-free ds_read_b128 (verified R3: 0).
// ============================================================================

// ---- GEMM1: Hw[t][e*HID+h] = bf16( w[t][e] * gelu(x @ W1[e] + b1[e]) ) ------
__global__ __launch_bounds__(256, 2)
void gemm1_kernel(const short* __restrict__ xb, const short* __restrict__ w1t,
                  const float* __restrict__ b1, const float* __restrict__ wgt,
                  short* __restrict__ hw) {
  const int e  = blockIdx.z;
  const int m0 = blockIdx.y * 128;
  const int n0 = blockIdx.x * 128;
  const int tid = threadIdx.x;
  const int lane = tid & 63;
  const int wv = tid >> 6;
  const int wm = (wv >> 1) * 64, wn = (wv & 1) * 64;
  const int quad = lane >> 4, lrow = lane & 15;
  const int sr  = tid >> 3;                        // staging row-in-call 0..31
  const int kof = ((tid & 7) ^ (sr & 7)) * 8;      // swizzled global k offset
  const int rkey = lrow & 7;                       // read-side swizzle key

  __shared__ __align__(16) short As[128 * 64];
  __shared__ __align__(16) short Bs[128 * 64];

  const short* Ap = xb;
  const short* Bp = w1t + (size_t)e * HID * DIM;

  floatx4 acc[4][4];
  #pragma unroll
  for (int i = 0; i < 4; i++)
    #pragma unroll
    for (int j = 0; j < 4; j++) acc[i][j] = (floatx4)0.f;

  for (int k0 = 0; k0 < DIM; k0 += 64) {
    __syncthreads();
    #pragma unroll
    for (int c = 0; c < 4; c++)
      async_cp16(Ap + (size_t)(m0 + c * 32 + sr) * DIM + k0 + kof,
                 As + (c * 256 + tid) * 8);
    #pragma unroll
    for (int c = 0; c < 4; c++)
      async_cp16(Bp + (size_t)(n0 + c * 32 + sr) * DIM + k0 + kof,
                 Bs + (c * 256 + tid) * 8);
    __syncthreads();
    #pragma unroll
    for (int kk = 0; kk < 2; kk++) {
      short8 af[4], bf[4];
      const int ko = ((kk * 4 + quad) ^ rkey) * 8;
      #pragma unroll
      for (int i = 0; i < 4; i++)
        af[i] = *(const short8*)&As[(wm + i * 16 + lrow) * 64 + ko];
      #pragma unroll
      for (int j = 0; j < 4; j++)
        bf[j] = *(const short8*)&Bs[(wn + j * 16 + lrow) * 64 + ko];
      #pragma unroll
      for (int i = 0; i < 4; i++)
        #pragma unroll
        for (int j = 0; j < 4; j++)
          acc[i][j] = __builtin_amdgcn_mfma_f32_16x16x32_bf16(af[i], bf[j], acc[i][j], 0, 0, 0);
    }
  }

  // epilogue: bias + fast gelu + router-weight fold + bf16 store
  #pragma unroll
  for (int i = 0; i < 4; i++) {
    const int rbase = m0 + wm + i * 16 + quad * 4;
    float wv4[4];
    #pragma unroll
    for (int r = 0; r < 4; r++) wv4[r] = wgt[(rbase + r) * NE + e];
    #pragma unroll
    for (int j = 0; j < 4; j++) {
      const int col = n0 + wn + j * 16 + lrow;          // h
      const float b = b1[e * HID + col];
      #pragma unroll
      for (int r = 0; r < 4; r++) {
        float v = acc[i][j][r] + b;
        hw[(size_t)(rbase + r) * KW + e * HID + col] = f2bf(wv4[r] * gelu_fast(v));
      }
    }
  }
}

// ---- GEMM2 (split-K, atomic combine): out += Hw @ W2t^T ---------------------
// out pre-initialized with weighted bias by bias_init.
__global__ __launch_bounds__(256, 2)
void gemm2_kernel(const short* __restrict__ hw, const short* __restrict__ w2t,
                  float* __restrict__ out) {
  const int kz = blockIdx.z;
  const int m0 = blockIdx.y * 128;
  const int n0 = blockIdx.x * 128;
  const int tid = threadIdx.x;
  const int lane = tid & 63;
  const int wv = tid >> 6;
  const int wm = (wv >> 1) * 64, wn = (wv & 1) * 64;
  const int quad = lane >> 4, lrow = lane & 15;
  const int sr  = tid >> 3;
  const int kof = ((tid & 7) ^ (sr & 7)) * 8;
  const int rkey = lrow & 7;

  __shared__ __align__(16) short As[128 * 64];
  __shared__ __align__(16) short Bs[128 * 64];

  floatx4 acc[4][4];
  #pragma unroll
  for (int i = 0; i < 4; i++)
    #pragma unroll
    for (int j = 0; j < 4; j++) acc[i][j] = (floatx4)0.f;

  const int kbeg = kz * KCH;
  for (int kk0 = 0; kk0 < KCH; kk0 += 64) {
    const int k0 = kbeg + kk0;
    __syncthreads();
    #pragma unroll
    for (int c = 0; c < 4; c++)
      async_cp16(hw + (size_t)(m0 + c * 32 + sr) * KW + k0 + kof,
                 As + (c * 256 + tid) * 8);
    #pragma unroll
    for (int c = 0; c < 4; c++)
      async_cp16(w2t + (size_t)(n0 + c * 32 + sr) * KW + k0 + kof,
                 Bs + (c * 256 + tid) * 8);
    __syncthreads();
    #pragma unroll
    for (int kk = 0; kk < 2; kk++) {
      short8 af[4], bf[4];
      const int ko = ((kk * 4 + quad) ^ rkey) * 8;
      #pragma unroll
      for (int i = 0; i < 4; i++)
        af[i] = *(const short8*)&As[(wm + i * 16 + lrow) * 64 + ko];
      #pragma unroll
      for (int j = 0; j < 4; j++)
        bf[j] = *(const short8*)&Bs[(wn + j * 16 + lrow) * 64 + ko];
      #pragma unroll
      for (int i = 0; i < 4; i++)
        #pragma unroll
        for (int j = 0; j < 4; j++)
          acc[i][j] = __builtin_amdgcn_mfma_f32_16x16x32_bf16(af[i], bf[j], acc[i][j], 0, 0, 0);
    }
  }

  #pragma unroll
  for (int i = 0; i < 4; i++) {
    const int rbase = m0 + wm + i * 16 + quad * 4;
    #pragma unroll
    for (int j = 0; j < 4; j++) {
      const int col = n0 + wn + j * 16 + lrow;
      #pragma unroll
      for (int r = 0; r < 4; r++)
        atomicAdd(&out[(size_t)(rbase + r) * DIM + col], acc[i][j][r]);
    }
  }
}

// ---- launch -----------------------------------------------------------------

extern "C" void kernel_launch(void* const* d_in, const int* in_sizes, int n_in,
                              void* d_out, int out_size, void* d_ws, size_t ws_size,
                              hipStream_t stream) {
  const float* x  = (const float*)d_in[0];
  const float* W1 = (const float*)d_in[1];
  const float* b1 = (const float*)d_in[2];
  const float* W2 = (const float*)d_in[3];
  const float* b2 = (const float*)d_in[4];
  const float* Wr = (const float*)d_in[5];
  const float* br = (const float*)d_in[6];
  float* out = (float*)d_out;

  // layout (bytes):
  //   wgt @ 0        64 KB   fp32 [NT][NE]
  //   w2t @ 64K      16 MB   bf16 [DIM][KW]
  //   hw  @ ~16.1M   64 MB   bf16 [NT][KW]
  //   xb  @ ~80.1M    8 MB   bf16 [NT][DIM]
  //   w1t @ ~88.5M   16 MB   bf16 [NE][HID][DIM]
  char* ws = (char*)d_ws;
  float* wgt = (float*)(ws);
  short* w2t = (short*)(ws + 65536);
  short* hw  = (short*)(ws + 65536 + 16777216);
  short* xb  = (short*)(ws + 65536 + 16777216 + 67108864);
  short* w1t = (short*)(ws + 65536 + 16777216 + 67108864 + 8388608);

  hipLaunchKernelGGL(router_cvt, dim3(NT / 4), dim3(256), 0, stream, x, Wr, br, wgt, xb);
  hipLaunchKernelGGL(transpose_cvt_fast, dim3(HID / 32, DIM / 128, NE), dim3(256), 0, stream,
                     W1, w1t, DIM, HID);
  hipLaunchKernelGGL(transpose_cvt_fast, dim3(DIM / 32, KW / 128, 1), dim3(256), 0, stream,
                     W2, w2t, KW, DIM);
  hipLaunchKernelGGL(bias_init, dim3(NT * DIM / 1024), dim3(256), 0, stream, wgt, b2, out);
  hipLaunchKernelGGL(gemm1_kernel, dim3(HID / 128, NT / 128, NE), dim3(256), 0, stream,
                     xb, w1t, b1, wgt, hw);
  hipLaunchKernelGGL(gemm2_kernel, dim3(DIM / 128, NT / 128, KSPLIT), dim3(256), 0, stream,
                     hw, w2t, out);
}

// Round 5
// 307.638 us; speedup vs baseline: 1.0703x; 1.0703x over previous
//
#include <hip/hip_runtime.h>
#include <hip/hip_bf16.h>
#include <math.h>

#define DIM 1024
#define HID 2048
#define NE  4
#define NT  4096            // B*T tokens
#define KW  (NE*HID)        // 8192, GEMM2 K / Hw leading dim
#define KSPLIT 4
#define KCH (KW / KSPLIT)   // 2048 per split

typedef __attribute__((ext_vector_type(8))) short short8;
typedef __attribute__((ext_vector_type(4))) short short4v;
typedef __attribute__((ext_vector_type(4))) float floatx4;

// ---- helpers ----------------------------------------------------------------

__device__ __forceinline__ void async_cp16(const void* g, void* l) {
  __builtin_amdgcn_global_load_lds(
      (const __attribute__((address_space(1))) void*)g,
      (__attribute__((address_space(3))) void*)l, 16, 0, 0);
}

__device__ __forceinline__ short f2bf(float f) {
  union { float f; unsigned u; } x; x.f = f;
  unsigned r = x.u + 0x7fffu + ((x.u >> 16) & 1u);   // round-to-nearest-even
  return (short)(r >> 16);
}

// fast GELU (tanh form via sigmoid + v_exp/v_rcp); |err| ~2e-4 vs exact
__device__ __forceinline__ float gelu_fast(float v) {
  float u = 1.595769122f * (v + 0.044715f * v * v * v);
  return v * __builtin_amdgcn_rcpf(1.0f + __expf(-u));
}

// ---- router + x->bf16: weights = softmax(x@Wr+br); xb = bf16(x) -------------
__global__ void router_cvt(const float* __restrict__ x, const float* __restrict__ Wr,
                           const float* __restrict__ br, float* __restrict__ wgt,
                           short* __restrict__ xb) {
  const int wv = threadIdx.x >> 6, lane = threadIdx.x & 63;
  const int t = blockIdx.x * 4 + wv;
  const float* xr = x + (size_t)t * DIM;
  short* xo = xb + (size_t)t * DIM;
  float a0 = 0.f, a1 = 0.f, a2 = 0.f, a3 = 0.f;
  #pragma unroll
  for (int p = 0; p < 4; p++) {
    const int d = p * 256 + lane * 4;
    floatx4 v = *(const floatx4*)&xr[d];
    short4v o;
    #pragma unroll
    for (int j = 0; j < 4; j++) {
      o[j] = f2bf(v[j]);
      floatx4 wr = *(const floatx4*)&Wr[(d + j) * 4];
      a0 += v[j] * wr[0]; a1 += v[j] * wr[1];
      a2 += v[j] * wr[2]; a3 += v[j] * wr[3];
    }
    *(short4v*)&xo[d] = o;
  }
  #pragma unroll
  for (int off = 32; off; off >>= 1) {
    a0 += __shfl_down(a0, off);
    a1 += __shfl_down(a1, off);
    a2 += __shfl_down(a2, off);
    a3 += __shfl_down(a3, off);
  }
  a0 = __shfl(a0, 0); a1 = __shfl(a1, 0); a2 = __shfl(a2, 0); a3 = __shfl(a3, 0);
  float s0 = a0 + br[0], s1 = a1 + br[1], s2 = a2 + br[2], s3 = a3 + br[3];
  float m = fmaxf(fmaxf(s0, s1), fmaxf(s2, s3));
  float e0 = __expf(s0 - m), e1 = __expf(s1 - m), e2 = __expf(s2 - m), e3 = __expf(s3 - m);
  float inv = 1.f / (e0 + e1 + e2 + e3);
  float v = (lane == 0) ? e0 : (lane == 1) ? e1 : (lane == 2) ? e2 : e3;
  if (lane < 4) wgt[t * 4 + lane] = v * inv;
}

// ---- merged weight transpose: W1 [E][DIM][HID]->[E][HID][DIM],
//      W2 [KW][DIM]->[DIM][KW]; fp32 in, bf16 out.
// tile 128 rows x 32 cols; float4 reads, b128 LDS reads + short8 writes.
#define TP_PADR 136   // LDS row stride (shorts); 272B, 16B-aligned
__global__ void transpose_all(const float* __restrict__ W1, short* __restrict__ w1t,
                              const float* __restrict__ W2, short* __restrict__ w2t) {
  __shared__ __align__(16) short tile[32 * TP_PADR];
  const int b = blockIdx.x;
  const float* in; short* out; int R, C, xt, yt;
  if (b < 2048) {                 // W1: per expert R=DIM rows, C=HID cols
    const int e = b >> 9, rem = b & 511;
    xt = rem & 63; yt = rem >> 6; R = DIM; C = HID;
    in = W1 + (size_t)e * DIM * HID; out = w1t + (size_t)e * DIM * HID;
  } else {                        // W2: R=KW rows, C=DIM cols
    const int rem = b - 2048;
    xt = rem & 31; yt = rem >> 5; R = KW; C = DIM;
    in = W2; out = w2t;
  }
  const int c0 = xt * 32, r0 = yt * 128;
  const int t = threadIdx.x;
  const int cin = (t & 7) * 4;
  const int rin = t >> 3;                 // 0..31
  #pragma unroll
  for (int i = 0; i < 4; i++) {
    const int r = rin + i * 32;
    floatx4 v = *(const floatx4*)&in[(size_t)(r0 + r) * C + c0 + cin];
    #pragma unroll
    for (int j = 0; j < 4; j++)
      tile[(cin + j) * TP_PADR + r] = f2bf(v[j]);
  }
  __syncthreads();
  const int ct = t >> 3;                  // 0..31
  #pragma unroll
  for (int i = 0; i < 2; i++) {
    const int rc = (t & 7) + 8 * i;       // 8-short chunks
    short8 vv = *(const short8*)&tile[ct * TP_PADR + rc * 8];
    *(short8*)&out[(size_t)(c0 + ct) * R + r0 + rc * 8] = vv;
  }
}

// ============================================================================
// GEMM tiles: 128x128, BK=64 (LDS 2x16KB), bf16 16x16x32 MFMA, 4 waves.
// LDS row stride 64 shorts (128B = all 32 banks); the 8x16B k-slots of row r
// hold k-block (pos ^ (r&7)) -> conflict-free ds_read_b128 (verified R3: 0).
// Split-K partials + streaming reduce beat atomicAdd combine (R4: +22us from
// L2 atomic serialization at equal HBM traffic).
// ============================================================================

// ---- GEMM1: Hw[t][e*HID+h] = bf16( w[t][e] * gelu(x @ W1[e] + b1[e]) ) ------
__global__ __launch_bounds__(256, 2)
void gemm1_kernel(const short* __restrict__ xb, const short* __restrict__ w1t,
                  const float* __restrict__ b1, const float* __restrict__ wgt,
                  short* __restrict__ hw) {
  const int e  = blockIdx.z;
  const int m0 = blockIdx.y * 128;
  const int n0 = blockIdx.x * 128;
  const int tid = threadIdx.x;
  const int lane = tid & 63;
  const int wv = tid >> 6;
  const int wm = (wv >> 1) * 64, wn = (wv & 1) * 64;
  const int quad = lane >> 4, lrow = lane & 15;
  const int sr  = tid >> 3;                        // staging row-in-call 0..31
  const int kof = ((tid & 7) ^ (sr & 7)) * 8;      // swizzled global k offset
  const int rkey = lrow & 7;                       // read-side swizzle key

  __shared__ __align__(16) short As[128 * 64];
  __shared__ __align__(16) short Bs[128 * 64];

  const short* Ap = xb;
  const short* Bp = w1t + (size_t)e * HID * DIM;

  floatx4 acc[4][4];
  #pragma unroll
  for (int i = 0; i < 4; i++)
    #pragma unroll
    for (int j = 0; j < 4; j++) acc[i][j] = (floatx4)0.f;

  for (int k0 = 0; k0 < DIM; k0 += 64) {
    __syncthreads();
    #pragma unroll
    for (int c = 0; c < 4; c++)
      async_cp16(Ap + (size_t)(m0 + c * 32 + sr) * DIM + k0 + kof,
                 As + (c * 256 + tid) * 8);
    #pragma unroll
    for (int c = 0; c < 4; c++)
      async_cp16(Bp + (size_t)(n0 + c * 32 + sr) * DIM + k0 + kof,
                 Bs + (c * 256 + tid) * 8);
    __syncthreads();
    #pragma unroll
    for (int kk = 0; kk < 2; kk++) {
      short8 af[4], bf[4];
      const int ko = ((kk * 4 + quad) ^ rkey) * 8;
      #pragma unroll
      for (int i = 0; i < 4; i++)
        af[i] = *(const short8*)&As[(wm + i * 16 + lrow) * 64 + ko];
      #pragma unroll
      for (int j = 0; j < 4; j++)
        bf[j] = *(const short8*)&Bs[(wn + j * 16 + lrow) * 64 + ko];
      #pragma unroll
      for (int i = 0; i < 4; i++)
        #pragma unroll
        for (int j = 0; j < 4; j++)
          acc[i][j] = __builtin_amdgcn_mfma_f32_16x16x32_bf16(af[i], bf[j], acc[i][j], 0, 0, 0);
    }
  }

  // epilogue: bias + fast gelu + router-weight fold + bf16 store
  #pragma unroll
  for (int i = 0; i < 4; i++) {
    const int rbase = m0 + wm + i * 16 + quad * 4;
    float wv4[4];
    #pragma unroll
    for (int r = 0; r < 4; r++) wv4[r] = wgt[(rbase + r) * NE + e];
    #pragma unroll
    for (int j = 0; j < 4; j++) {
      const int col = n0 + wn + j * 16 + lrow;          // h
      const float b = b1[e * HID + col];
      #pragma unroll
      for (int r = 0; r < 4; r++) {
        float v = acc[i][j][r] + b;
        hw[(size_t)(rbase + r) * KW + e * HID + col] = f2bf(wv4[r] * gelu_fast(v));
      }
    }
  }
}

// ---- GEMM2 (split-K): out[t][d] = Hw @ W2t^T + sum_e w[t][e]*b2[e][d] -------
// kz==0 writes out (+weighted bias); kz>0 writes fp32 partials.
__global__ __launch_bounds__(256, 2)
void gemm2_kernel(const short* __restrict__ hw, const short* __restrict__ w2t,
                  const float* __restrict__ b2, const float* __restrict__ wgt,
                  float* __restrict__ out, float* __restrict__ part) {
  const int kz = blockIdx.z;
  const int m0 = blockIdx.y * 128;
  const int n0 = blockIdx.x * 128;
  const int tid = threadIdx.x;
  const int lane = tid & 63;
  const int wv = tid >> 6;
  const int wm = (wv >> 1) * 64, wn = (wv & 1) * 64;
  const int quad = lane >> 4, lrow = lane & 15;
  const int sr  = tid >> 3;
  const int kof = ((tid & 7) ^ (sr & 7)) * 8;
  const int rkey = lrow & 7;

  __shared__ __align__(16) short As[128 * 64];
  __shared__ __align__(16) short Bs[128 * 64];

  floatx4 acc[4][4];
  #pragma unroll
  for (int i = 0; i < 4; i++)
    #pragma unroll
    for (int j = 0; j < 4; j++) acc[i][j] = (floatx4)0.f;

  const int kbeg = kz * KCH;
  for (int kk0 = 0; kk0 < KCH; kk0 += 64) {
    const int k0 = kbeg + kk0;
    __syncthreads();
    #pragma unroll
    for (int c = 0; c < 4; c++)
      async_cp16(hw + (size_t)(m0 + c * 32 + sr) * KW + k0 + kof,
                 As + (c * 256 + tid) * 8);
    #pragma unroll
    for (int c = 0; c < 4; c++)
      async_cp16(w2t + (size_t)(n0 + c * 32 + sr) * KW + k0 + kof,
                 Bs + (c * 256 + tid) * 8);
    __syncthreads();
    #pragma unroll
    for (int kk = 0; kk < 2; kk++) {
      short8 af[4], bf[4];
      const int ko = ((kk * 4 + quad) ^ rkey) * 8;
      #pragma unroll
      for (int i = 0; i < 4; i++)
        af[i] = *(const short8*)&As[(wm + i * 16 + lrow) * 64 + ko];
      #pragma unroll
      for (int j = 0; j < 4; j++)
        bf[j] = *(const short8*)&Bs[(wn + j * 16 + lrow) * 64 + ko];
      #pragma unroll
      for (int i = 0; i < 4; i++)
        #pragma unroll
        for (int j = 0; j < 4; j++)
          acc[i][j] = __builtin_amdgcn_mfma_f32_16x16x32_bf16(af[i], bf[j], acc[i][j], 0, 0, 0);
    }
  }

  if (kz == 0) {
    #pragma unroll
    for (int i = 0; i < 4; i++) {
      const int rbase = m0 + wm + i * 16 + quad * 4;
      floatx4 wr[4];
      #pragma unroll
      for (int r = 0; r < 4; r++) wr[r] = *(const floatx4*)&wgt[(rbase + r) * NE];
      #pragma unroll
      for (int j = 0; j < 4; j++) {
        const int col = n0 + wn + j * 16 + lrow;
        float b2v[4];
        #pragma unroll
        for (int eI = 0; eI < 4; eI++) b2v[eI] = b2[eI * DIM + col];
        #pragma unroll
        for (int r = 0; r < 4; r++) {
          float bias = wr[r][0] * b2v[0] + wr[r][1] * b2v[1] +
                       wr[r][2] * b2v[2] + wr[r][3] * b2v[3];
          out[(size_t)(rbase + r) * DIM + col] = acc[i][j][r] + bias;
        }
      }
    }
  } else {
    float* p = part + (size_t)(kz - 1) * NT * DIM;
    #pragma unroll
    for (int i = 0; i < 4; i++) {
      const int rbase = m0 + wm + i * 16 + quad * 4;
      #pragma unroll
      for (int j = 0; j < 4; j++) {
        const int col = n0 + wn + j * 16 + lrow;
        #pragma unroll
        for (int r = 0; r < 4; r++)
          p[(size_t)(rbase + r) * DIM + col] = acc[i][j][r];
      }
    }
  }
}

// ---- reduce: out += p0 + p1 + p2 -------------------------------------------
__global__ void reduce_out(float* __restrict__ out, const float* __restrict__ part) {
  int i = (blockIdx.x * 256 + threadIdx.x) * 4;
  floatx4 v = *(const floatx4*)&out[i];
  floatx4 a = *(const floatx4*)&part[i];
  floatx4 b = *(const floatx4*)&part[i + NT * DIM];
  floatx4 c = *(const floatx4*)&part[i + 2 * NT * DIM];
  v = v + a + b + c;
  *(floatx4*)&out[i] = v;
}

// ---- launch -----------------------------------------------------------------

extern "C" void kernel_launch(void* const* d_in, const int* in_sizes, int n_in,
                              void* d_out, int out_size, void* d_ws, size_t ws_size,
                              hipStream_t stream) {
  const float* x  = (const float*)d_in[0];
  const float* W1 = (const float*)d_in[1];
  const float* b1 = (const float*)d_in[2];
  const float* W2 = (const float*)d_in[3];
  const float* b2 = (const float*)d_in[4];
  const float* Wr = (const float*)d_in[5];
  const float* br = (const float*)d_in[6];
  float* out = (float*)d_out;

  // layout (bytes):
  //   wgt  @ 0        64 KB   fp32 [NT][NE]
  //   w2t  @ 64K      16 MB   bf16 [DIM][KW]
  //   hw   @ ~16.1M   64 MB   bf16 [NT][KW]
  //   xb   @ ~80.1M    8 MB   bf16 [NT][DIM]     (dead after gemm1)
  //   w1t  @ ~88.5M   16 MB   bf16 [NE][HID][DIM](dead after gemm1)
  //   part @ ~80.1M   48 MB   fp32 [3][NT][DIM]  (aliases xb+w1t+tail)
  char* ws = (char*)d_ws;
  float* wgt = (float*)(ws);
  short* w2t = (short*)(ws + 65536);
  short* hw  = (short*)(ws + 65536 + 16777216);
  short* xb  = (short*)(ws + 65536 + 16777216 + 67108864);
  short* w1t = (short*)(ws + 65536 + 16777216 + 67108864 + 8388608);
  float* part= (float*)(ws + 65536 + 16777216 + 67108864);   // aliases xb/w1t

  hipLaunchKernelGGL(router_cvt, dim3(NT / 4), dim3(256), 0, stream, x, Wr, br, wgt, xb);
  hipLaunchKernelGGL(transpose_all, dim3(2048 + 2048), dim3(256), 0, stream,
                     W1, w1t, W2, w2t);
  hipLaunchKernelGGL(gemm1_kernel, dim3(HID / 128, NT / 128, NE), dim3(256), 0, stream,
                     xb, w1t, b1, wgt, hw);
  hipLaunchKernelGGL(gemm2_kernel, dim3(DIM / 128, NT / 128, KSPLIT), dim3(256), 0, stream,
                     hw, w2t, b2, wgt, out, part);
  hipLaunchKernelGGL(reduce_out, dim3(NT * DIM / 1024), dim3(256), 0, stream, out, part);
}

// Round 6
// 284.085 us; speedup vs baseline: 1.1590x; 1.0829x over previous
//
#include <hip/hip_runtime.h>
#include <hip/hip_bf16.h>
#include <math.h>

#define DIM 1024
#define HID 2048
#define NE  4
#define NT  4096            // B*T tokens
#define KW  (NE*HID)        // 8192, GEMM2 K / Hw leading dim
#define KSPLIT 2
#define KCH (KW / KSPLIT)   // 4096 per split

typedef __attribute__((ext_vector_type(8))) short short8;
typedef __attribute__((ext_vector_type(4))) short short4v;
typedef __attribute__((ext_vector_type(4))) float floatx4;

// ---- helpers ----------------------------------------------------------------

__device__ __forceinline__ void async_cp16(const void* g, void* l) {
  __builtin_amdgcn_global_load_lds(
      (const __attribute__((address_space(1))) void*)g,
      (__attribute__((address_space(3))) void*)l, 16, 0, 0);
}

__device__ __forceinline__ short f2bf(float f) {
  union { float f; unsigned u; } x; x.f = f;
  unsigned r = x.u + 0x7fffu + ((x.u >> 16) & 1u);   // round-to-nearest-even
  return (short)(r >> 16);
}

// fast GELU (tanh form via sigmoid + v_exp/v_rcp); |err| ~2e-4 vs exact
__device__ __forceinline__ float gelu_fast(float v) {
  float u = 1.595769122f * (v + 0.044715f * v * v * v);
  return v * __builtin_amdgcn_rcpf(1.0f + __expf(-u));
}

// ---- router + x->bf16: weights = softmax(x@Wr+br); xb = bf16(x) -------------
__global__ void router_cvt(const float* __restrict__ x, const float* __restrict__ Wr,
                           const float* __restrict__ br, float* __restrict__ wgt,
                           short* __restrict__ xb) {
  const int wv = threadIdx.x >> 6, lane = threadIdx.x & 63;
  const int t = blockIdx.x * 4 + wv;
  const float* xr = x + (size_t)t * DIM;
  short* xo = xb + (size_t)t * DIM;
  float a0 = 0.f, a1 = 0.f, a2 = 0.f, a3 = 0.f;
  #pragma unroll
  for (int p = 0; p < 4; p++) {
    const int d = p * 256 + lane * 4;
    floatx4 v = *(const floatx4*)&xr[d];
    short4v o;
    #pragma unroll
    for (int j = 0; j < 4; j++) {
      o[j] = f2bf(v[j]);
      floatx4 wr = *(const floatx4*)&Wr[(d + j) * 4];
      a0 += v[j] * wr[0]; a1 += v[j] * wr[1];
      a2 += v[j] * wr[2]; a3 += v[j] * wr[3];
    }
    *(short4v*)&xo[d] = o;
  }
  #pragma unroll
  for (int off = 32; off; off >>= 1) {
    a0 += __shfl_down(a0, off);
    a1 += __shfl_down(a1, off);
    a2 += __shfl_down(a2, off);
    a3 += __shfl_down(a3, off);
  }
  a0 = __shfl(a0, 0); a1 = __shfl(a1, 0); a2 = __shfl(a2, 0); a3 = __shfl(a3, 0);
  float s0 = a0 + br[0], s1 = a1 + br[1], s2 = a2 + br[2], s3 = a3 + br[3];
  float m = fmaxf(fmaxf(s0, s1), fmaxf(s2, s3));
  float e0 = __expf(s0 - m), e1 = __expf(s1 - m), e2 = __expf(s2 - m), e3 = __expf(s3 - m);
  float inv = 1.f / (e0 + e1 + e2 + e3);
  float v = (lane == 0) ? e0 : (lane == 1) ? e1 : (lane == 2) ? e2 : e3;
  if (lane < 4) wgt[t * 4 + lane] = v * inv;
}

// ---- merged weight transpose: W1 [E][DIM][HID]->[E][HID][DIM],
//      W2 [KW][DIM]->[DIM][KW]; fp32 in, bf16 out.
#define TP_PADR 136   // LDS row stride (shorts); 272B, 16B-aligned
__global__ void transpose_all(const float* __restrict__ W1, short* __restrict__ w1t,
                              const float* __restrict__ W2, short* __restrict__ w2t) {
  __shared__ __align__(16) short tile[32 * TP_PADR];
  const int b = blockIdx.x;
  const float* in; short* out; int R, C, xt, yt;
  if (b < 2048) {                 // W1: per expert R=DIM rows, C=HID cols
    const int e = b >> 9, rem = b & 511;
    xt = rem & 63; yt = rem >> 6; R = DIM; C = HID;
    in = W1 + (size_t)e * DIM * HID; out = w1t + (size_t)e * DIM * HID;
  } else {                        // W2: R=KW rows, C=DIM cols
    const int rem = b - 2048;
    xt = rem & 31; yt = rem >> 5; R = KW; C = DIM;
    in = W2; out = w2t;
  }
  const int c0 = xt * 32, r0 = yt * 128;
  const int t = threadIdx.x;
  const int cin = (t & 7) * 4;
  const int rin = t >> 3;                 // 0..31
  #pragma unroll
  for (int i = 0; i < 4; i++) {
    const int r = rin + i * 32;
    floatx4 v = *(const floatx4*)&in[(size_t)(r0 + r) * C + c0 + cin];
    #pragma unroll
    for (int j = 0; j < 4; j++)
      tile[(cin + j) * TP_PADR + r] = f2bf(v[j]);
  }
  __syncthreads();
  const int ct = t >> 3;                  // 0..31
  #pragma unroll
  for (int i = 0; i < 2; i++) {
    const int rc = (t & 7) + 8 * i;       // 8-short chunks
    short8 vv = *(const short8*)&tile[ct * TP_PADR + rc * 8];
    *(short8*)&out[(size_t)(c0 + ct) * R + r0 + rc * 8] = vv;
  }
}

// ============================================================================
// GEMM tiles: 128x128, BK=64 (LDS 2x16KB), bf16 16x16x32 MFMA, 4 waves.
// LDS row stride 64 shorts; k-slots XOR-swizzled (verified: 0 bank conflicts).
// Split-K partials + streaming reduce (atomicAdd combine regressed 22us, R4).
// XCD-aware 1-D grid decode: dispatch is round-robin over 8 XCDs (bid&7), so
// each XCD gets a brick of blocks sharing A- and B-slices -> per-XCD L2
// unique working set drops ~3x (R5: gemm2 FETCH 271MB vs 80MB unique).
// ============================================================================

// ---- GEMM1: Hw[t][e*HID+h] = bf16( w[t][e] * gelu(x @ W1[e] + b1[e]) ) ------
// grid: 2048 blocks 1-D. XCD brick: 8 m x 16 n x 2 e (A shared across e).
__global__ __launch_bounds__(256, 2)
void gemm1_kernel(const short* __restrict__ xb, const short* __restrict__ w1t,
                  const float* __restrict__ b1, const float* __restrict__ wgt,
                  short* __restrict__ hw) {
  const int b = blockIdx.x;
  const int xcd = b & 7, slot = b >> 3;            // slot 0..255
  const int m_grp = xcd & 3, e_pair = xcd >> 1 & 2; // e_pair in {0,2}
  const int n_idx = slot & 15, m_off = (slot >> 4) & 7, e_off = slot >> 7;
  const int e  = (xcd >> 2) * 2 + e_off;
  const int m0 = (m_grp * 8 + m_off) * 128;
  const int n0 = n_idx * 128;
  (void)e_pair;
  const int tid = threadIdx.x;
  const int lane = tid & 63;
  const int wv = tid >> 6;
  const int wm = (wv >> 1) * 64, wn = (wv & 1) * 64;
  const int quad = lane >> 4, lrow = lane & 15;
  const int sr  = tid >> 3;                        // staging row-in-call 0..31
  const int kof = ((tid & 7) ^ (sr & 7)) * 8;      // swizzled global k offset
  const int rkey = lrow & 7;                       // read-side swizzle key

  __shared__ __align__(16) short As[128 * 64];
  __shared__ __align__(16) short Bs[128 * 64];

  const short* Ap = xb;
  const short* Bp = w1t + (size_t)e * HID * DIM;

  floatx4 acc[4][4];
  #pragma unroll
  for (int i = 0; i < 4; i++)
    #pragma unroll
    for (int j = 0; j < 4; j++) acc[i][j] = (floatx4)0.f;

  for (int k0 = 0; k0 < DIM; k0 += 64) {
    __syncthreads();
    #pragma unroll
    for (int c = 0; c < 4; c++)
      async_cp16(Ap + (size_t)(m0 + c * 32 + sr) * DIM + k0 + kof,
                 As + (c * 256 + tid) * 8);
    #pragma unroll
    for (int c = 0; c < 4; c++)
      async_cp16(Bp + (size_t)(n0 + c * 32 + sr) * DIM + k0 + kof,
                 Bs + (c * 256 + tid) * 8);
    __syncthreads();
    #pragma unroll
    for (int kk = 0; kk < 2; kk++) {
      short8 af[4], bf[4];
      const int ko = ((kk * 4 + quad) ^ rkey) * 8;
      #pragma unroll
      for (int i = 0; i < 4; i++)
        af[i] = *(const short8*)&As[(wm + i * 16 + lrow) * 64 + ko];
      #pragma unroll
      for (int j = 0; j < 4; j++)
        bf[j] = *(const short8*)&Bs[(wn + j * 16 + lrow) * 64 + ko];
      #pragma unroll
      for (int i = 0; i < 4; i++)
        #pragma unroll
        for (int j = 0; j < 4; j++)
          acc[i][j] = __builtin_amdgcn_mfma_f32_16x16x32_bf16(af[i], bf[j], acc[i][j], 0, 0, 0);
    }
  }

  // epilogue: bias + fast gelu + router-weight fold + bf16 store
  #pragma unroll
  for (int i = 0; i < 4; i++) {
    const int rbase = m0 + wm + i * 16 + quad * 4;
    float wv4[4];
    #pragma unroll
    for (int r = 0; r < 4; r++) wv4[r] = wgt[(rbase + r) * NE + e];
    #pragma unroll
    for (int j = 0; j < 4; j++) {
      const int col = n0 + wn + j * 16 + lrow;          // h
      const float b1v = b1[e * HID + col];
      #pragma unroll
      for (int r = 0; r < 4; r++) {
        float v = acc[i][j][r] + b1v;
        hw[(size_t)(rbase + r) * KW + e * HID + col] = f2bf(wv4[r] * gelu_fast(v));
      }
    }
  }
}

// ---- GEMM2 (split-K=2): out[t][d] = Hw @ W2t^T + sum_e w[t][e]*b2[e][d] -----
// grid: 512 blocks 1-D. XCD brick: 8 m x 8 n x 1 kz.
// kz==0 writes out (+weighted bias); kz==1 writes fp32 partial.
__global__ __launch_bounds__(256, 2)
void gemm2_kernel(const short* __restrict__ hw, const short* __restrict__ w2t,
                  const float* __restrict__ b2, const float* __restrict__ wgt,
                  float* __restrict__ out, float* __restrict__ part) {
  const int b = blockIdx.x;
  const int xcd = b & 7, slot = b >> 3;            // slot 0..63
  const int m_grp = xcd & 3, kz = xcd >> 2;
  const int n_idx = slot & 7, m_off = slot >> 3;
  const int m0 = (m_grp * 8 + m_off) * 128;
  const int n0 = n_idx * 128;
  const int tid = threadIdx.x;
  const int lane = tid & 63;
  const int wv = tid >> 6;
  const int wm = (wv >> 1) * 64, wn = (wv & 1) * 64;
  const int quad = lane >> 4, lrow = lane & 15;
  const int sr  = tid >> 3;
  const int kof = ((tid & 7) ^ (sr & 7)) * 8;
  const int rkey = lrow & 7;

  __shared__ __align__(16) short As[128 * 64];
  __shared__ __align__(16) short Bs[128 * 64];

  floatx4 acc[4][4];
  #pragma unroll
  for (int i = 0; i < 4; i++)
    #pragma unroll
    for (int j = 0; j < 4; j++) acc[i][j] = (floatx4)0.f;

  const int kbeg = kz * KCH;
  for (int kk0 = 0; kk0 < KCH; kk0 += 64) {
    const int k0 = kbeg + kk0;
    __syncthreads();
    #pragma unroll
    for (int c = 0; c < 4; c++)
      async_cp16(hw + (size_t)(m0 + c * 32 + sr) * KW + k0 + kof,
                 As + (c * 256 + tid) * 8);
    #pragma unroll
    for (int c = 0; c < 4; c++)
      async_cp16(w2t + (size_t)(n0 + c * 32 + sr) * KW + k0 + kof,
                 Bs + (c * 256 + tid) * 8);
    __syncthreads();
    #pragma unroll
    for (int kk = 0; kk < 2; kk++) {
      short8 af[4], bf[4];
      const int ko = ((kk * 4 + quad) ^ rkey) * 8;
      #pragma unroll
      for (int i = 0; i < 4; i++)
        af[i] = *(const short8*)&As[(wm + i * 16 + lrow) * 64 + ko];
      #pragma unroll
      for (int j = 0; j < 4; j++)
        bf[j] = *(const short8*)&Bs[(wn + j * 16 + lrow) * 64 + ko];
      #pragma unroll
      for (int i = 0; i < 4; i++)
        #pragma unroll
        for (int j = 0; j < 4; j++)
          acc[i][j] = __builtin_amdgcn_mfma_f32_16x16x32_bf16(af[i], bf[j], acc[i][j], 0, 0, 0);
    }
  }

  if (kz == 0) {
    #pragma unroll
    for (int i = 0; i < 4; i++) {
      const int rbase = m0 + wm + i * 16 + quad * 4;
      floatx4 wr[4];
      #pragma unroll
      for (int r = 0; r < 4; r++) wr[r] = *(const floatx4*)&wgt[(rbase + r) * NE];
      #pragma unroll
      for (int j = 0; j < 4; j++) {
        const int col = n0 + wn + j * 16 + lrow;
        float b2v[4];
        #pragma unroll
        for (int eI = 0; eI < 4; eI++) b2v[eI] = b2[eI * DIM + col];
        #pragma unroll
        for (int r = 0; r < 4; r++) {
          float bias = wr[r][0] * b2v[0] + wr[r][1] * b2v[1] +
                       wr[r][2] * b2v[2] + wr[r][3] * b2v[3];
          out[(size_t)(rbase + r) * DIM + col] = acc[i][j][r] + bias;
        }
      }
    }
  } else {
    #pragma unroll
    for (int i = 0; i < 4; i++) {
      const int rbase = m0 + wm + i * 16 + quad * 4;
      #pragma unroll
      for (int j = 0; j < 4; j++) {
        const int col = n0 + wn + j * 16 + lrow;
        #pragma unroll
        for (int r = 0; r < 4; r++)
          part[(size_t)(rbase + r) * DIM + col] = acc[i][j][r];
      }
    }
  }
}

// ---- reduce: out += part ----------------------------------------------------
__global__ void reduce_out(float* __restrict__ out, const float* __restrict__ part) {
  int i = (blockIdx.x * 256 + threadIdx.x) * 4;
  floatx4 v = *(const floatx4*)&out[i];
  floatx4 a = *(const floatx4*)&part[i];
  v = v + a;
  *(floatx4*)&out[i] = v;
}

// ---- launch -----------------------------------------------------------------

extern "C" void kernel_launch(void* const* d_in, const int* in_sizes, int n_in,
                              void* d_out, int out_size, void* d_ws, size_t ws_size,
                              hipStream_t stream) {
  const float* x  = (const float*)d_in[0];
  const float* W1 = (const float*)d_in[1];
  const float* b1 = (const float*)d_in[2];
  const float* W2 = (const float*)d_in[3];
  const float* b2 = (const float*)d_in[4];
  const float* Wr = (const float*)d_in[5];
  const float* br = (const float*)d_in[6];
  float* out = (float*)d_out;

  // layout (bytes):
  //   wgt  @ 0        64 KB   fp32 [NT][NE]
  //   w2t  @ 64K      16 MB   bf16 [DIM][KW]
  //   hw   @ ~16.1M   64 MB   bf16 [NT][KW]
  //   xb   @ ~80.1M    8 MB   bf16 [NT][DIM]     (dead after gemm1)
  //   w1t  @ ~88.5M   16 MB   bf16 [NE][HID][DIM](dead after gemm1)
  //   part @ ~80.1M   16 MB   fp32 [NT][DIM]     (aliases xb+w1t head)
  char* ws = (char*)d_ws;
  float* wgt = (float*)(ws);
  short* w2t = (short*)(ws + 65536);
  short* hw  = (short*)(ws + 65536 + 16777216);
  short* xb  = (short*)(ws + 65536 + 16777216 + 67108864);
  short* w1t = (short*)(ws + 65536 + 16777216 + 67108864 + 8388608);
  float* part= (float*)(ws + 65536 + 16777216 + 67108864);   // aliases xb/w1t

  hipLaunchKernelGGL(router_cvt, dim3(NT / 4), dim3(256), 0, stream, x, Wr, br, wgt, xb);
  hipLaunchKernelGGL(transpose_all, dim3(2048 + 2048), dim3(256), 0, stream,
                     W1, w1t, W2, w2t);
  hipLaunchKernelGGL(gemm1_kernel, dim3(2048), dim3(256), 0, stream,
                     xb, w1t, b1, wgt, hw);
  hipLaunchKernelGGL(gemm2_kernel, dim3(512), dim3(256), 0, stream,
                     hw, w2t, b2, wgt, out, part);
  hipLaunchKernelGGL(reduce_out, dim3(NT * DIM / 1024), dim3(256), 0, stream, out, part);
}